// Round 7
// baseline (1634.999 us; speedup 1.0000x reference)
//
#include <hip/hip_runtime.h>

// ---------------------------------------------------------------------------
// SentBERT_RNN: recurrence is over the BATCH axis (64 steps), carry (T=256,H).
// All low-precision tensors are FP16; fp32 accumulation throughout.
// R7: lstm all-gather traffic halved: 32 WGs/dir (N=64 gate-rows, 16 units
// per WG; weights = 256 VGPRs/lane), so aggregate LLC h-read is 16 MB/step
// instead of 32. Flags padded to 64B slots (no same-line atomic pileup).
// ---------------------------------------------------------------------------

typedef _Float16 f16x8 __attribute__((ext_vector_type(8)));
typedef float f32x4 __attribute__((ext_vector_type(4)));
typedef unsigned short us4 __attribute__((ext_vector_type(4)));
typedef unsigned short us8 __attribute__((ext_vector_type(8)));
typedef unsigned int u32x4 __attribute__((ext_vector_type(4)));

#define DEV __device__ __forceinline__

DEV unsigned short f2h(float f) {
  _Float16 h = (_Float16)f;  // v_cvt_f16_f32, RNE
  return __builtin_bit_cast(unsigned short, h);
}
DEV float h2f(unsigned short u) {
  return (float)__builtin_bit_cast(_Float16, u);
}
DEV float sigf(float x) { return 1.f / (1.f + __expf(-x)); }
DEV float tanhf_(float x) { return 1.f - 2.f / (__expf(2.f * x) + 1.f); }

// LLC-coherent (L1/L2-bypass) 16B store.
DEV void store_b128_llc(unsigned short* addr, us8 v) {
  asm volatile("global_store_dwordx4 %0, %1, off sc0 sc1" ::"v"(addr), "v"(v)
               : "memory");
}
DEV void waitcnt_vm0() { asm volatile("s_waitcnt vmcnt(0)" ::: "memory"); }

// 16 LLC-coherent 16B loads (stride 64B) + drain. Outputs ready on return.
DEV void load_frags16_llc(const unsigned short* base, f16x8 af[16]) {
  asm volatile(
      "global_load_dwordx4 %0, %16, off sc0 sc1\n\t"
      "global_load_dwordx4 %1, %16, off offset:64 sc0 sc1\n\t"
      "global_load_dwordx4 %2, %16, off offset:128 sc0 sc1\n\t"
      "global_load_dwordx4 %3, %16, off offset:192 sc0 sc1\n\t"
      "global_load_dwordx4 %4, %16, off offset:256 sc0 sc1\n\t"
      "global_load_dwordx4 %5, %16, off offset:320 sc0 sc1\n\t"
      "global_load_dwordx4 %6, %16, off offset:384 sc0 sc1\n\t"
      "global_load_dwordx4 %7, %16, off offset:448 sc0 sc1\n\t"
      "global_load_dwordx4 %8, %16, off offset:512 sc0 sc1\n\t"
      "global_load_dwordx4 %9, %16, off offset:576 sc0 sc1\n\t"
      "global_load_dwordx4 %10, %16, off offset:640 sc0 sc1\n\t"
      "global_load_dwordx4 %11, %16, off offset:704 sc0 sc1\n\t"
      "global_load_dwordx4 %12, %16, off offset:768 sc0 sc1\n\t"
      "global_load_dwordx4 %13, %16, off offset:832 sc0 sc1\n\t"
      "global_load_dwordx4 %14, %16, off offset:896 sc0 sc1\n\t"
      "global_load_dwordx4 %15, %16, off offset:960 sc0 sc1\n\t"
      "s_waitcnt vmcnt(0)"
      : "=v"(af[0]), "=v"(af[1]), "=v"(af[2]), "=v"(af[3]), "=v"(af[4]),
        "=v"(af[5]), "=v"(af[6]), "=v"(af[7]), "=v"(af[8]), "=v"(af[9]),
        "=v"(af[10]), "=v"(af[11]), "=v"(af[12]), "=v"(af[13]), "=v"(af[14]),
        "=v"(af[15])
      : "v"(base)
      : "memory");
}

// ---------------------------------------------------------------------------
// prep kernel
// ---------------------------------------------------------------------------
DEV void cvt4seg(const float* __restrict__ src, unsigned short* __restrict__ dst,
                 size_t nquads, size_t gt, size_t NT) {
  const f32x4* s4 = (const f32x4*)src;
  us4* d4 = (us4*)dst;
  for (size_t i = gt; i < nquads; i += NT) {
    f32x4 v = s4[i];
    us4 o = {f2h(v[0]), f2h(v[1]), f2h(v[2]), f2h(v[3])};
    d4[i] = o;
  }
}

__global__ __launch_bounds__(256, 1) void prep_kernel(
    const float* __restrict__ emb, const float* __restrict__ wihf,
    const float* __restrict__ whhf, const float* __restrict__ bf_,
    const float* __restrict__ wihb, const float* __restrict__ whhb,
    const float* __restrict__ bb_, const float* __restrict__ posemb,
    const float* __restrict__ Wnov, const float* __restrict__ wabs,
    unsigned short* __restrict__ emb_t, unsigned short* __restrict__ wcat,
    unsigned short* __restrict__ whh, unsigned short* __restrict__ WnT,
    float* __restrict__ bcat, float* __restrict__ absp,
    unsigned short* __restrict__ hst, int* __restrict__ cnt) {
  size_t gt = (size_t)blockIdx.x * 256 + threadIdx.x;
  size_t NT = (size_t)gridDim.x * 256;
  // emb (T,B,E) f32 -> emb_t[b*256+t][e] fp16  (row-transposed)
  for (size_t i = gt; i < 3145728u; i += NT) {  // 16384 rows * 192 quads
    size_t r = i / 192, e4 = i % 192;
    size_t b = r >> 8, t = r & 255;
    f32x4 v = *(const f32x4*)(emb + (t * 64 + b) * 768 + e4 * 4);
    us4 o = {f2h(v[0]), f2h(v[1]), f2h(v[2]), f2h(v[3])};
    ((us4*)emb_t)[i] = o;
  }
  cvt4seg(wihf, wcat, 393216u, gt, NT);                 // 2048*768 /4
  cvt4seg(wihb, wcat + 1572864, 393216u, gt, NT);
  cvt4seg(whhf, whh, 262144u, gt, NT);                  // 2048*512 /4
  cvt4seg(whhb, whh + 1048576, 262144u, gt, NT);
  // W_nov transpose: WnT[k][h] = W_nov[h][k]
  for (size_t i = gt; i < 1048576u; i += NT) {
    size_t k = i >> 10, h = i & 1023;
    WnT[i] = f2h(Wnov[h * 1024 + k]);
  }
  for (size_t i = gt; i < 4096u; i += NT)
    bcat[i] = (i < 2048) ? bf_[i] : bb_[i - 2048];
  for (size_t i = gt; i < 256u; i += NT) {
    float a = 0.f;
    for (int p = 0; p < 100; ++p) a += posemb[i * 100 + p] * wabs[p];
    absp[i] = a;
  }
  // zero h ping-pong state: 2 dirs x 2 parities x 256 x 512 fp16 = 1 MB
  u32x4 z = {0u, 0u, 0u, 0u};
  for (size_t i = gt; i < 65536u; i += NT) ((u32x4*)hst)[i] = z;
  // zero flag array (2 dirs x 32 slots x 16 ints, 64B padded)
  for (size_t i = gt; i < 2048u; i += NT) cnt[i] = 0;
}

// ---------------------------------------------------------------------------
// GEMM: C[M][N] = A[M][K] * B[N][K]^T (+bias[m]); A,B fp16 K-major.
// ---------------------------------------------------------------------------
template <int BIAS, int OF16>
__global__ __launch_bounds__(256, 2) void gemm_bt(
    const unsigned short* __restrict__ A, const unsigned short* __restrict__ B,
    void* __restrict__ C, const float* __restrict__ bias, int M, int N, int K) {
  __shared__ __align__(16) unsigned short As[128 * 32];
  __shared__ __align__(16) unsigned short Bs[128 * 32];
  const int tid = threadIdx.x;
  const size_t m0 = (size_t)blockIdx.x * 128, n0 = (size_t)blockIdx.y * 128;
  const int w = tid >> 6, l = tid & 63;
  const int rh = (w >> 1) * 64, ch = (w & 1) * 64;
  const int lm = l >> 4, ln = l & 15;
  f32x4 acc[4][4] = {};
  us8 pa[2], pb[2];
#pragma unroll
  for (int p = 0; p < 2; ++p) {
    int idx = p * 256 + tid, row = idx >> 2, kq = idx & 3;
    pa[p] = *(const us8*)(A + (m0 + row) * (size_t)K + kq * 8);
    pb[p] = *(const us8*)(B + (n0 + row) * (size_t)K + kq * 8);
  }
  for (int k0 = 0; k0 < K; k0 += 32) {
    __syncthreads();
#pragma unroll
    for (int p = 0; p < 2; ++p) {
      int idx = p * 256 + tid;
      *(us8*)&As[idx * 8] = pa[p];
      *(us8*)&Bs[idx * 8] = pb[p];
    }
    __syncthreads();
    if (k0 + 32 < K) {
#pragma unroll
      for (int p = 0; p < 2; ++p) {
        int idx = p * 256 + tid, row = idx >> 2, kq = idx & 3;
        pa[p] = *(const us8*)(A + (m0 + row) * (size_t)K + (k0 + 32) + kq * 8);
        pb[p] = *(const us8*)(B + (n0 + row) * (size_t)K + (k0 + 32) + kq * 8);
      }
    }
    f16x8 af[4], bfv[4];
#pragma unroll
    for (int r = 0; r < 4; ++r)
      af[r] = *(const f16x8*)&As[(rh + r * 16 + ln) * 32 + lm * 8];
#pragma unroll
    for (int c = 0; c < 4; ++c)
      bfv[c] = *(const f16x8*)&Bs[(ch + c * 16 + ln) * 32 + lm * 8];
#pragma unroll
    for (int r = 0; r < 4; ++r)
#pragma unroll
      for (int c = 0; c < 4; ++c)
        acc[r][c] =
            __builtin_amdgcn_mfma_f32_16x16x32_f16(af[r], bfv[c], acc[r][c], 0, 0, 0);
  }
#pragma unroll
  for (int r = 0; r < 4; ++r) {
#pragma unroll
    for (int reg = 0; reg < 4; ++reg) {
      size_t rowg = m0 + rh + r * 16 + lm * 4 + reg;
      float bv = BIAS ? bias[rowg] : 0.f;
#pragma unroll
      for (int c = 0; c < 4; ++c) {
        size_t col = n0 + ch + c * 16 + ln;
        float v = acc[r][c][reg] + bv;
        if (OF16)
          ((unsigned short*)C)[rowg * N + col] = f2h(v);
        else
          ((float*)C)[rowg * N + col] = v;
      }
    }
  }
}

// ---------------------------------------------------------------------------
// Persistent batch-axis BiLSTM. 64 WGs x 256 threads (4 waves).
//   WG = (dir d, unit-slice s: 16 units -> 64 gate-rows in VGPRs, 256/lane).
//   Chains = 256 t-rows, M-split 64/wave. 64 sequential steps over batch.
//   Sync: bypass-coherent h (sc0 sc1), padded per-WG flag slots (64B),
//   wave0 lane-parallel poll. No cache-maintenance ops.
// ---------------------------------------------------------------------------
__global__ __launch_bounds__(256, 1) void lstm_kernel(
    const unsigned short* __restrict__ whh,  // [2][2048][512] fp16
    const unsigned short* __restrict__ pre,  // [4096][16384] fp16, col=b*256+t
    unsigned short* __restrict__ hst,        // [2][2][256][512] fp16 ping-pong
    unsigned short* __restrict__ hsd,        // [64][256][1024] fp16
    int* __restrict__ cnt) {                 // [2][32] slots x16 ints (64B)
  const int wg = blockIdx.x;
  const int d = wg >> 5, s = wg & 31;
  const int u0 = s * 16;
  const int tid = threadIdx.x, wv = tid >> 6, l = tid & 63;
  const int lm = l >> 4, ln = l & 15;
  __shared__ __align__(16) float gbuf[4][64 * 65];

  // Weight fragments, resident across all steps: 64 gate-rows.
  // n = nf*16 + ln: gate q = nf, unit du = ln -> w_hh row q*512 + u0 + du.
  f16x8 wf[4][16];
#pragma unroll
  for (int nf = 0; nf < 4; ++nf) {
    const unsigned short* wrow =
        whh + ((size_t)d * 2048 + (size_t)nf * 512 + u0 + ln) * 512;
#pragma unroll
    for (int kc = 0; kc < 16; ++kc)
      wf[nf][kc] = *(const f16x8*)(wrow + kc * 32 + lm * 8);
  }
  float cst[16];
#pragma unroll
  for (int j = 0; j < 16; ++j) cst[j] = 0.f;
  int* flags = cnt + d * 512;  // 32 slots x 16 ints

  for (int step = 0; step < 64; ++step) {
    const int b_eff = d ? (63 - step) : step;
    // prefetch this step's pre slice (independent of h) before the spin
    us4 pv[4][4];
#pragma unroll
    for (int mt = 0; mt < 4; ++mt)
#pragma unroll
      for (int nf = 0; nf < 4; ++nf) {
        pv[mt][nf] = *(const us4*)(pre +
            ((size_t)d * 2048 + (size_t)nf * 512 + u0 + ln) * 16384 +
            b_eff * 256 + wv * 64 + mt * 16 + lm * 4);
      }
    if (step > 0) {
      if (wv == 0) {
        const int idx = (l & 31) * 16;
        for (;;) {
          int v = __hip_atomic_load(flags + idx, __ATOMIC_RELAXED,
                                    __HIP_MEMORY_SCOPE_AGENT);
          if (__ballot(v < step) == 0ull) break;
          __builtin_amdgcn_s_sleep(1);
        }
      }
      __syncthreads();
    }
    const unsigned short* hbase =
        hst + ((size_t)d * 2 + (step & 1)) * (256 * 512);
#pragma unroll
    for (int mt = 0; mt < 4; ++mt) {
      const int trow = wv * 64 + mt * 16 + ln;  // A: m = lane&15
      f16x8 af[16];
      load_frags16_llc(hbase + (size_t)trow * 512 + lm * 8, af);
      f32x4 acc[4] = {};
#pragma unroll
      for (int kc = 0; kc < 16; ++kc) {
#pragma unroll
        for (int nf = 0; nf < 4; ++nf)
          acc[nf] = __builtin_amdgcn_mfma_f32_16x16x32_f16(af[kc], wf[nf][kc],
                                                           acc[nf], 0, 0, 0);
      }
      // add input projection, scatter to LDS (D: row=quad*4+reg, col=lane&15)
#pragma unroll
      for (int nf = 0; nf < 4; ++nf) {
        int n = nf * 16 + ln;
#pragma unroll
        for (int reg = 0; reg < 4; ++reg)
          gbuf[wv][(mt * 16 + lm * 4 + reg) * 65 + n] =
              acc[nf][reg] + h2f(pv[mt][nf][reg]);
      }
    }
    __syncthreads();
    // gate math: lane l owns chain t = wv*64+l, units du=0..15
    {
      const float* gb = &gbuf[wv][l * 65];
      us8 hv0, hv1;
#pragma unroll
      for (int du = 0; du < 16; ++du) {
        float gi = gb[du];
        float gf = gb[16 + du];
        float gg = gb[32 + du];
        float go = gb[48 + du];
        float cn = sigf(gf) * cst[du] + sigf(gi) * tanhf_(gg);
        cst[du] = cn;
        float h = sigf(go) * tanhf_(cn);
        if (du < 8) hv0[du] = f2h(h);
        else hv1[du - 8] = f2h(h);
      }
      const int t = wv * 64 + l;
      unsigned short* hdst = hst +
          ((size_t)d * 2 + ((step & 1) ^ 1)) * (256 * 512) + (size_t)t * 512 + u0;
      store_b128_llc(hdst, hv0);
      store_b128_llc(hdst + 8, hv1);
      unsigned short* sdst =
          hsd + ((size_t)(b_eff * 256 + t)) * 1024 + d * 512 + u0;
      *(us8*)sdst = hv0;
      *(us8*)(sdst + 8) = hv1;
    }
    waitcnt_vm0();   // h slice at LLC (coherence point)
    __syncthreads();
    if (tid == 0)
      __hip_atomic_store(flags + s * 16, step + 1, __ATOMIC_RELAXED,
                         __HIP_MEMORY_SCOPE_AGENT);
  }
}

// ---------------------------------------------------------------------------
// hsum[b][j] = sum_t hsd[b][t][j]  (f32 accum)
// ---------------------------------------------------------------------------
__global__ __launch_bounds__(256, 1) void hsum_kernel(
    const unsigned short* __restrict__ hsd, float* __restrict__ hsum) {
  int b = blockIdx.x, tid = threadIdx.x;
  const unsigned short* base = hsd + (size_t)b * 256 * 1024 + tid * 4;
  f32x4 acc = {};
  for (int t = 0; t < 256; ++t) {
    us4 v = *(const us4*)(base + t * 1024);
    acc[0] += h2f(v[0]);
    acc[1] += h2f(v[1]);
    acc[2] += h2f(v[2]);
    acc[3] += h2f(v[3]);
  }
  *(f32x4*)(hsum + (size_t)b * 1024 + tid * 4) = acc;
}

// ---------------------------------------------------------------------------
// y[b][k] = maybe_tanh( dot(W[k][:], x[b][:]) * scale + bias[k] )
// ---------------------------------------------------------------------------
__global__ __launch_bounds__(256, 1) void rowdot_kernel(
    const float* __restrict__ W, const float* __restrict__ x,
    const float* __restrict__ bias, float* __restrict__ y, float scale,
    int do_tanh) {
  int gt = blockIdx.x * 256 + threadIdx.x;  // 65536 = 64*1024
  int b = gt >> 10, k = gt & 1023;
  const f32x4* wr = (const f32x4*)(W + (size_t)k * 1024);
  const f32x4* xr = (const f32x4*)(x + (size_t)b * 1024);
  float acc = 0.f;
  for (int j = 0; j < 256; ++j) {
    f32x4 wv = wr[j], xv = xr[j];
    acc += wv[0] * xv[0] + wv[1] * xv[1] + wv[2] * xv[2] + wv[3] * xv[3];
  }
  acc = acc * scale + (bias ? bias[k] : 0.f);
  y[gt] = do_tanh ? tanhf_(acc) : acc;
}

// ---------------------------------------------------------------------------
// s0[b][t] = hsd[b,t,:].w_content + hsd[b,t,:].d2[b,:] + absp[t] + bias
// ---------------------------------------------------------------------------
__global__ __launch_bounds__(256, 1) void s0_kernel(
    const unsigned short* __restrict__ hsd, const float* __restrict__ wcont,
    const float* __restrict__ d2, const float* __restrict__ absp,
    const float* __restrict__ biasp, float* __restrict__ s0) {
  int tid = threadIdx.x, wv = tid >> 6, l = tid & 63;
  int idx = blockIdx.x * 4 + wv;  // b*256+t
  int b = idx >> 8, t = idx & 255;
  const unsigned short* hr = hsd + (size_t)idx * 1024 + l * 16;
  const float* wc = wcont + l * 16;
  const float* dr = d2 + (size_t)b * 1024 + l * 16;
  float sc = 0.f, ss = 0.f;
#pragma unroll
  for (int j = 0; j < 16; ++j) {
    float hf = h2f(hr[j]);
    sc += hf * wc[j];
    ss += hf * dr[j];
  }
#pragma unroll
  for (int off = 32; off; off >>= 1) {
    sc += __shfl_down(sc, off);
    ss += __shfl_down(ss, off);
  }
  if (l == 0) s0[idx] = sc + ss + absp[t] + biasp[0];
}

// ---------------------------------------------------------------------------
// Sequential novelty scan over t. One block per batch; summ in regs 4/thread.
// ---------------------------------------------------------------------------
__global__ __launch_bounds__(256, 1) void scan_kernel(
    const float* __restrict__ Anov, const unsigned short* __restrict__ hsd,
    const float* __restrict__ s0, float* __restrict__ out) {
  int b = blockIdx.x, tid = threadIdx.x, wv = tid >> 6, l = tid & 63;
  __shared__ float red[4];
  float summ[4] = {0.f, 0.f, 0.f, 0.f};
  const float* Ab = Anov + (size_t)b * 256 * 1024 + tid * 4;
  const unsigned short* hb = hsd + (size_t)b * 256 * 1024 + tid * 4;
  const float* sb = s0 + b * 256;
  float* ob = out + b * 256;
  f32x4 a = *(const f32x4*)Ab;
  us4 hv = *(const us4*)hb;
  for (int t = 0; t < 256; ++t) {
    f32x4 ac = a;
    us4 hc = hv;
    if (t < 255) {  // prefetch next iter, independent of the dependent chain
      a = *(const f32x4*)(Ab + (t + 1) * 1024);
      hv = *(const us4*)(hb + (t + 1) * 1024);
    }
    float p = ac[0] * tanhf_(summ[0]) + ac[1] * tanhf_(summ[1]) +
              ac[2] * tanhf_(summ[2]) + ac[3] * tanhf_(summ[3]);
#pragma unroll
    for (int off = 32; off; off >>= 1) p += __shfl_down(p, off);
    if (l == 0) red[wv] = p;
    __syncthreads();
    float nov = red[0] + red[1] + red[2] + red[3];
    float prob = sigf(sb[t] - nov);
    summ[0] += prob * h2f(hc[0]);
    summ[1] += prob * h2f(hc[1]);
    summ[2] += prob * h2f(hc[2]);
    summ[3] += prob * h2f(hc[3]);
    if (tid == 0) ob[t] = prob;
    __syncthreads();
  }
}

// ---------------------------------------------------------------------------
extern "C" void kernel_launch(void* const* d_in, const int* in_sizes, int n_in,
                              void* d_out, int out_size, void* d_ws,
                              size_t ws_size, hipStream_t stream) {
  const float* emb = (const float*)d_in[0];
  const float* wihf = (const float*)d_in[2];
  const float* whhf = (const float*)d_in[3];
  const float* bf_ = (const float*)d_in[4];
  const float* wihb = (const float*)d_in[5];
  const float* whhb = (const float*)d_in[6];
  const float* bb_ = (const float*)d_in[7];
  const float* Wfdoc = (const float*)d_in[8];
  const float* bfdoc = (const float*)d_in[9];
  const float* posemb = (const float*)d_in[10];
  const float* wcont = (const float*)d_in[11];
  const float* Wsal = (const float*)d_in[12];
  const float* Wnov = (const float*)d_in[13];
  const float* wabs = (const float*)d_in[14];
  const float* biasp = (const float*)d_in[15];

  char* ws = (char*)d_ws;
  unsigned short* PRE = (unsigned short*)(ws + 0);  // 134217728 B
  float* Anov = (float*)(ws + 0);                   // 67108864 B (reuses PRE)
  unsigned short* emb_t = (unsigned short*)(ws + 134217728);  // 25165824
  unsigned short* wcat = (unsigned short*)(ws + 159383552);   // 6291456
  unsigned short* whh = (unsigned short*)(ws + 165675008);    // 4194304
  unsigned short* WnT = (unsigned short*)(ws + 169869312);    // 2097152
  unsigned short* hsd = (unsigned short*)(ws + 171966464);    // 33554432
  unsigned short* hst = (unsigned short*)(ws + 205520896);    // 1048576
  float* hsum = (float*)(ws + 206569472);                     // 262144
  float* doc = (float*)(ws + 206831616);                      // 262144
  float* d2 = (float*)(ws + 207093760);                       // 262144
  float* s0 = (float*)(ws + 207355904);                       // 65536
  float* absp = (float*)(ws + 207421440);                     // 1024
  float* bcat = (float*)(ws + 207422464);                     // 16384
  int* cnt = (int*)(ws + 207438848);                          // 8192
  float* out = (float*)d_out;

  prep_kernel<<<dim3(2048), dim3(256), 0, stream>>>(
      emb, wihf, whhf, bf_, wihb, whhb, bb_, posemb, Wnov, wabs, emb_t, wcat,
      whh, WnT, bcat, absp, hst, cnt);
  gemm_bt<1, 1><<<dim3(32, 128), dim3(256), 0, stream>>>(
      wcat, emb_t, (void*)PRE, bcat, 4096, 16384, 768);
  lstm_kernel<<<dim3(64), dim3(256), 0, stream>>>(whh, PRE, hst, hsd, cnt);
  hsum_kernel<<<dim3(64), dim3(256), 0, stream>>>(hsd, hsum);
  rowdot_kernel<<<dim3(256), dim3(256), 0, stream>>>(Wfdoc, hsum, bfdoc, doc,
                                                     1.f / 256.f, 1);
  rowdot_kernel<<<dim3(256), dim3(256), 0, stream>>>(Wsal, doc, (const float*)nullptr,
                                                     d2, 1.f, 0);
  s0_kernel<<<dim3(4096), dim3(256), 0, stream>>>(hsd, wcont, d2, absp, biasp, s0);
  gemm_bt<0, 0><<<dim3(128, 8), dim3(256), 0, stream>>>(
      hsd, WnT, (void*)Anov, (const float*)nullptr, 16384, 1024, 1024);
  scan_kernel<<<dim3(64), dim3(256), 0, stream>>>(Anov, hsd, s0, out);
}

// Round 9
// 1063.289 us; speedup vs baseline: 1.5377x; 1.5377x over previous
//
#include <hip/hip_runtime.h>

// ---------------------------------------------------------------------------
// SentBERT_RNN: recurrence is over the BATCH axis (64 steps), carry (T=256,H).
// All low-precision tensors are FP16; fp32 accumulation throughout.
// R9 = R8 structure with the load-wait bug fixed: the s_waitcnt vmcnt(0) is
// back INSIDE each 16-load asm block (R8 split it out; the compiler then
// scheduled MFMAs before the wait -> NaN). 256 WGs (dir x t-half x 64
// row-slices), 1/CU; per-WG gather 128 KB/step; 64-wide sync groups;
// hsd store after flag release.
// ---------------------------------------------------------------------------

typedef _Float16 f16x8 __attribute__((ext_vector_type(8)));
typedef float f32x4 __attribute__((ext_vector_type(4)));
typedef unsigned short us4 __attribute__((ext_vector_type(4)));
typedef unsigned short us8 __attribute__((ext_vector_type(8)));
typedef unsigned int u32x4 __attribute__((ext_vector_type(4)));

#define DEV __device__ __forceinline__

DEV unsigned short f2h(float f) {
  _Float16 h = (_Float16)f;  // v_cvt_f16_f32, RNE
  return __builtin_bit_cast(unsigned short, h);
}
DEV float h2f(unsigned short u) {
  return (float)__builtin_bit_cast(_Float16, u);
}
DEV float sigf(float x) { return 1.f / (1.f + __expf(-x)); }
DEV float tanhf_(float x) { return 1.f - 2.f / (__expf(2.f * x) + 1.f); }

// LLC-coherent (L1/L2-bypass) 8B store.
DEV void store_b64_llc(unsigned short* addr, us4 v) {
  asm volatile("global_store_dwordx2 %0, %1, off sc0 sc1" ::"v"(addr), "v"(v)
               : "memory");
}
DEV void waitcnt_vm0() { asm volatile("s_waitcnt vmcnt(0)" ::: "memory"); }

// 16 LLC-coherent 16B loads (stride 64B) + internal drain. Outputs are
// architecturally ready when the block completes (wait INSIDE the block —
// do not split it out; consumer scheduling is not ordered by a separate
// waitcnt block).
DEV void load_frags16_llc(const unsigned short* base, f16x8 af[16]) {
  asm volatile(
      "global_load_dwordx4 %0, %16, off sc0 sc1\n\t"
      "global_load_dwordx4 %1, %16, off offset:64 sc0 sc1\n\t"
      "global_load_dwordx4 %2, %16, off offset:128 sc0 sc1\n\t"
      "global_load_dwordx4 %3, %16, off offset:192 sc0 sc1\n\t"
      "global_load_dwordx4 %4, %16, off offset:256 sc0 sc1\n\t"
      "global_load_dwordx4 %5, %16, off offset:320 sc0 sc1\n\t"
      "global_load_dwordx4 %6, %16, off offset:384 sc0 sc1\n\t"
      "global_load_dwordx4 %7, %16, off offset:448 sc0 sc1\n\t"
      "global_load_dwordx4 %8, %16, off offset:512 sc0 sc1\n\t"
      "global_load_dwordx4 %9, %16, off offset:576 sc0 sc1\n\t"
      "global_load_dwordx4 %10, %16, off offset:640 sc0 sc1\n\t"
      "global_load_dwordx4 %11, %16, off offset:704 sc0 sc1\n\t"
      "global_load_dwordx4 %12, %16, off offset:768 sc0 sc1\n\t"
      "global_load_dwordx4 %13, %16, off offset:832 sc0 sc1\n\t"
      "global_load_dwordx4 %14, %16, off offset:896 sc0 sc1\n\t"
      "global_load_dwordx4 %15, %16, off offset:960 sc0 sc1\n\t"
      "s_waitcnt vmcnt(0)"
      : "=v"(af[0]), "=v"(af[1]), "=v"(af[2]), "=v"(af[3]), "=v"(af[4]),
        "=v"(af[5]), "=v"(af[6]), "=v"(af[7]), "=v"(af[8]), "=v"(af[9]),
        "=v"(af[10]), "=v"(af[11]), "=v"(af[12]), "=v"(af[13]), "=v"(af[14]),
        "=v"(af[15])
      : "v"(base)
      : "memory");
}

// ---------------------------------------------------------------------------
// prep kernel
// ---------------------------------------------------------------------------
DEV void cvt4seg(const float* __restrict__ src, unsigned short* __restrict__ dst,
                 size_t nquads, size_t gt, size_t NT) {
  const f32x4* s4 = (const f32x4*)src;
  us4* d4 = (us4*)dst;
  for (size_t i = gt; i < nquads; i += NT) {
    f32x4 v = s4[i];
    us4 o = {f2h(v[0]), f2h(v[1]), f2h(v[2]), f2h(v[3])};
    d4[i] = o;
  }
}

__global__ __launch_bounds__(256, 1) void prep_kernel(
    const float* __restrict__ emb, const float* __restrict__ wihf,
    const float* __restrict__ whhf, const float* __restrict__ bf_,
    const float* __restrict__ wihb, const float* __restrict__ whhb,
    const float* __restrict__ bb_, const float* __restrict__ posemb,
    const float* __restrict__ Wnov, const float* __restrict__ wabs,
    unsigned short* __restrict__ emb_t, unsigned short* __restrict__ wcat,
    unsigned short* __restrict__ whh, unsigned short* __restrict__ WnT,
    float* __restrict__ bcat, float* __restrict__ absp,
    unsigned short* __restrict__ hst, int* __restrict__ cnt) {
  size_t gt = (size_t)blockIdx.x * 256 + threadIdx.x;
  size_t NT = (size_t)gridDim.x * 256;
  // emb (T,B,E) f32 -> emb_t[b*256+t][e] fp16  (row-transposed)
  for (size_t i = gt; i < 3145728u; i += NT) {  // 16384 rows * 192 quads
    size_t r = i / 192, e4 = i % 192;
    size_t b = r >> 8, t = r & 255;
    f32x4 v = *(const f32x4*)(emb + (t * 64 + b) * 768 + e4 * 4);
    us4 o = {f2h(v[0]), f2h(v[1]), f2h(v[2]), f2h(v[3])};
    ((us4*)emb_t)[i] = o;
  }
  cvt4seg(wihf, wcat, 393216u, gt, NT);                 // 2048*768 /4
  cvt4seg(wihb, wcat + 1572864, 393216u, gt, NT);
  cvt4seg(whhf, whh, 262144u, gt, NT);                  // 2048*512 /4
  cvt4seg(whhb, whh + 1048576, 262144u, gt, NT);
  // W_nov transpose: WnT[k][h] = W_nov[h][k]
  for (size_t i = gt; i < 1048576u; i += NT) {
    size_t k = i >> 10, h = i & 1023;
    WnT[i] = f2h(Wnov[h * 1024 + k]);
  }
  for (size_t i = gt; i < 4096u; i += NT)
    bcat[i] = (i < 2048) ? bf_[i] : bb_[i - 2048];
  for (size_t i = gt; i < 256u; i += NT) {
    float a = 0.f;
    for (int p = 0; p < 100; ++p) a += posemb[i * 100 + p] * wabs[p];
    absp[i] = a;
  }
  // zero h ping-pong state: 2 dirs x 2 parities x 256 x 512 fp16 = 1 MB
  u32x4 z = {0u, 0u, 0u, 0u};
  for (size_t i = gt; i < 65536u; i += NT) ((u32x4*)hst)[i] = z;
  // zero flag array (4 groups x 64 compact ints, plus slack)
  for (size_t i = gt; i < 2048u; i += NT) cnt[i] = 0;
}

// ---------------------------------------------------------------------------
// GEMM: C[M][N] = A[M][K] * B[N][K]^T (+bias[m]); A,B fp16 K-major.
// ---------------------------------------------------------------------------
template <int BIAS, int OF16>
__global__ __launch_bounds__(256, 2) void gemm_bt(
    const unsigned short* __restrict__ A, const unsigned short* __restrict__ B,
    void* __restrict__ C, const float* __restrict__ bias, int M, int N, int K) {
  __shared__ __align__(16) unsigned short As[128 * 32];
  __shared__ __align__(16) unsigned short Bs[128 * 32];
  const int tid = threadIdx.x;
  const size_t m0 = (size_t)blockIdx.x * 128, n0 = (size_t)blockIdx.y * 128;
  const int w = tid >> 6, l = tid & 63;
  const int rh = (w >> 1) * 64, ch = (w & 1) * 64;
  const int lm = l >> 4, ln = l & 15;
  f32x4 acc[4][4] = {};
  us8 pa[2], pb[2];
#pragma unroll
  for (int p = 0; p < 2; ++p) {
    int idx = p * 256 + tid, row = idx >> 2, kq = idx & 3;
    pa[p] = *(const us8*)(A + (m0 + row) * (size_t)K + kq * 8);
    pb[p] = *(const us8*)(B + (n0 + row) * (size_t)K + kq * 8);
  }
  for (int k0 = 0; k0 < K; k0 += 32) {
    __syncthreads();
#pragma unroll
    for (int p = 0; p < 2; ++p) {
      int idx = p * 256 + tid;
      *(us8*)&As[idx * 8] = pa[p];
      *(us8*)&Bs[idx * 8] = pb[p];
    }
    __syncthreads();
    if (k0 + 32 < K) {
#pragma unroll
      for (int p = 0; p < 2; ++p) {
        int idx = p * 256 + tid, row = idx >> 2, kq = idx & 3;
        pa[p] = *(const us8*)(A + (m0 + row) * (size_t)K + (k0 + 32) + kq * 8);
        pb[p] = *(const us8*)(B + (n0 + row) * (size_t)K + (k0 + 32) + kq * 8);
      }
    }
    f16x8 af[4], bfv[4];
#pragma unroll
    for (int r = 0; r < 4; ++r)
      af[r] = *(const f16x8*)&As[(rh + r * 16 + ln) * 32 + lm * 8];
#pragma unroll
    for (int c = 0; c < 4; ++c)
      bfv[c] = *(const f16x8*)&Bs[(ch + c * 16 + ln) * 32 + lm * 8];
#pragma unroll
    for (int r = 0; r < 4; ++r)
#pragma unroll
      for (int c = 0; c < 4; ++c)
        acc[r][c] =
            __builtin_amdgcn_mfma_f32_16x16x32_f16(af[r], bfv[c], acc[r][c], 0, 0, 0);
  }
#pragma unroll
  for (int r = 0; r < 4; ++r) {
#pragma unroll
    for (int reg = 0; reg < 4; ++reg) {
      size_t rowg = m0 + rh + r * 16 + lm * 4 + reg;
      float bv = BIAS ? bias[rowg] : 0.f;
#pragma unroll
      for (int c = 0; c < 4; ++c) {
        size_t col = n0 + ch + c * 16 + ln;
        float v = acc[r][c][reg] + bv;
        if (OF16)
          ((unsigned short*)C)[rowg * N + col] = f2h(v);
        else
          ((float*)C)[rowg * N + col] = v;
      }
    }
  }
}

// ---------------------------------------------------------------------------
// Persistent batch-axis BiLSTM. 256 WGs x 256 threads (4 waves), 1 WG/CU.
//   WG = (dir d, t-half ts: 128 chains, row-slice s: 8 units -> 32 gate-rows
//   in VGPRs). Per wave: 32 chains (2 MFMA m-tiles). 64 steps over batch.
//   Sync: groups of 64 WGs (same d, ts) via compact flags; h via sc0 sc1
//   LLC-coherent ops. Gate math is a wave-private LDS roundtrip.
// ---------------------------------------------------------------------------
__global__ __launch_bounds__(256, 1) void lstm_kernel(
    const unsigned short* __restrict__ whh,  // [2][2048][512] fp16
    const unsigned short* __restrict__ pre,  // [4096][16384] fp16, col=b*256+t
    unsigned short* __restrict__ hst,        // [2][2][256][512] fp16 ping-pong
    unsigned short* __restrict__ hsd,        // [64][256][1024] fp16
    int* __restrict__ cnt) {                 // [2][2][64] compact flags
  const int wg = blockIdx.x;
  const int d = wg >> 7;
  const int sub = wg & 127;
  const int ts = sub >> 6;  // t-half: chains ts*128 .. ts*128+127
  const int s = sub & 63;   // row slice: units u0..u0+7
  const int u0 = s * 8;
  const int tid = threadIdx.x, wv = tid >> 6, l = tid & 63;
  const int lm = l >> 4, ln = l & 15;
  __shared__ __align__(16) float gbuf[4][32 * 33];

  // Weight fragments, resident across all steps.
  // n in [0,32): gate q = n>>3, unit du = n&7 -> w_hh row q*512 + u0 + du.
  f16x8 wf[2][16];
#pragma unroll
  for (int c = 0; c < 2; ++c) {
    int n = c * 16 + ln;
    const unsigned short* wrow =
        whh + ((size_t)d * 2048 + (size_t)(n >> 3) * 512 + u0 + (n & 7)) * 512;
#pragma unroll
    for (int kc = 0; kc < 16; ++kc)
      wf[c][kc] = *(const f16x8*)(wrow + kc * 32 + lm * 8);
  }
  float cst[4] = {0.f, 0.f, 0.f, 0.f};
  int* flags = cnt + (d * 2 + ts) * 64;
  const int chain0 = ts * 128 + wv * 32;  // wave's first chain

  for (int step = 0; step < 64; ++step) {
    const int b_eff = d ? (63 - step) : step;
    // prefetch this step's pre slice (independent of h) before the spin
    us4 pv[2][2];
#pragma unroll
    for (int mt = 0; mt < 2; ++mt)
#pragma unroll
      for (int c = 0; c < 2; ++c) {
        int n = c * 16 + ln;
        pv[mt][c] = *(const us4*)(pre +
            ((size_t)d * 2048 + (size_t)(n >> 3) * 512 + u0 + (n & 7)) * 16384 +
            b_eff * 256 + chain0 + mt * 16 + lm * 4);
      }
    if (step > 0) {
      if (wv == 0) {
        for (;;) {
          int v = __hip_atomic_load(flags + l, __ATOMIC_RELAXED,
                                    __HIP_MEMORY_SCOPE_AGENT);
          if (__ballot(v < step) == 0ull) break;
          __builtin_amdgcn_s_sleep(1);
        }
      }
      __syncthreads();
    }
    float pvf[2][2][4];
#pragma unroll
    for (int mt = 0; mt < 2; ++mt)
#pragma unroll
      for (int c = 0; c < 2; ++c)
#pragma unroll
        for (int reg = 0; reg < 4; ++reg) pvf[mt][c][reg] = h2f(pv[mt][c][reg]);

    const unsigned short* hbase =
        hst + ((size_t)d * 2 + (step & 1)) * (256 * 512);
#pragma unroll
    for (int mt = 0; mt < 2; ++mt) {
      f16x8 af[16];
      load_frags16_llc(hbase + (size_t)(chain0 + mt * 16 + ln) * 512 + lm * 8,
                       af);
      f32x4 a0 = {}, a1 = {};
#pragma unroll
      for (int kc = 0; kc < 16; ++kc) {
        a0 = __builtin_amdgcn_mfma_f32_16x16x32_f16(af[kc], wf[0][kc], a0, 0, 0, 0);
        a1 = __builtin_amdgcn_mfma_f32_16x16x32_f16(af[kc], wf[1][kc], a1, 0, 0, 0);
      }
      // scatter gates+pre to LDS (D layout: row = quad*4+reg, col = lane&15)
#pragma unroll
      for (int c = 0; c < 2; ++c) {
        int n = c * 16 + ln;
        f32x4 A = c ? a1 : a0;
#pragma unroll
        for (int reg = 0; reg < 4; ++reg)
          gbuf[wv][(mt * 16 + lm * 4 + reg) * 33 + n] =
              A[reg] + pvf[mt][c][reg];
      }
    }
    // gate math: wave-private LDS roundtrip (compiler inserts lgkmcnt).
    // lane l -> chain l>>1, unit group (l&1)*4.
    us4 hv;
    const int t = chain0 + (l >> 1);
    {
      const float* gb = &gbuf[wv][(l >> 1) * 33];
      const int ug = (l & 1) * 4;
#pragma unroll
      for (int j = 0; j < 4; ++j) {
        int du = ug + j;
        float gi = gb[du];
        float gf = gb[8 + du];
        float gg = gb[16 + du];
        float go = gb[24 + du];
        float cn = sigf(gf) * cst[j] + sigf(gi) * tanhf_(gg);
        cst[j] = cn;
        hv[j] = f2h(sigf(go) * tanhf_(cn));
      }
      store_b64_llc(hst + ((size_t)d * 2 + ((step & 1) ^ 1)) * (256 * 512) +
                        (size_t)t * 512 + u0 + ug,
                    hv);
    }
    waitcnt_vm0();   // h slice acked at LLC (coherence point)
    __syncthreads();
    if (tid == 0)
      __hip_atomic_store(flags + s, step + 1, __ATOMIC_RELAXED,
                         __HIP_MEMORY_SCOPE_AGENT);
    // hsd store AFTER release: off the critical path (drained at kernel end)
    *(us4*)(hsd + ((size_t)(b_eff * 256 + t)) * 1024 + d * 512 + u0 +
            (l & 1) * 4) = hv;
  }
}

// ---------------------------------------------------------------------------
// hsum[b][j] = sum_t hsd[b][t][j]  (f32 accum)
// ---------------------------------------------------------------------------
__global__ __launch_bounds__(256, 1) void hsum_kernel(
    const unsigned short* __restrict__ hsd, float* __restrict__ hsum) {
  int b = blockIdx.x, tid = threadIdx.x;
  const unsigned short* base = hsd + (size_t)b * 256 * 1024 + tid * 4;
  f32x4 acc = {};
  for (int t = 0; t < 256; ++t) {
    us4 v = *(const us4*)(base + t * 1024);
    acc[0] += h2f(v[0]);
    acc[1] += h2f(v[1]);
    acc[2] += h2f(v[2]);
    acc[3] += h2f(v[3]);
  }
  *(f32x4*)(hsum + (size_t)b * 1024 + tid * 4) = acc;
}

// ---------------------------------------------------------------------------
// y[b][k] = maybe_tanh( dot(W[k][:], x[b][:]) * scale + bias[k] )
// ---------------------------------------------------------------------------
__global__ __launch_bounds__(256, 1) void rowdot_kernel(
    const float* __restrict__ W, const float* __restrict__ x,
    const float* __restrict__ bias, float* __restrict__ y, float scale,
    int do_tanh) {
  int gt = blockIdx.x * 256 + threadIdx.x;  // 65536 = 64*1024
  int b = gt >> 10, k = gt & 1023;
  const f32x4* wr = (const f32x4*)(W + (size_t)k * 1024);
  const f32x4* xr = (const f32x4*)(x + (size_t)b * 1024);
  float acc = 0.f;
  for (int j = 0; j < 256; ++j) {
    f32x4 wv = wr[j], xv = xr[j];
    acc += wv[0] * xv[0] + wv[1] * xv[1] + wv[2] * xv[2] + wv[3] * xv[3];
  }
  acc = acc * scale + (bias ? bias[k] : 0.f);
  y[gt] = do_tanh ? tanhf_(acc) : acc;
}

// ---------------------------------------------------------------------------
// s0[b][t] = hsd[b,t,:].w_content + hsd[b,t,:].d2[b,:] + absp[t] + bias
// ---------------------------------------------------------------------------
__global__ __launch_bounds__(256, 1) void s0_kernel(
    const unsigned short* __restrict__ hsd, const float* __restrict__ wcont,
    const float* __restrict__ d2, const float* __restrict__ absp,
    const float* __restrict__ biasp, float* __restrict__ s0) {
  int tid = threadIdx.x, wv = tid >> 6, l = tid & 63;
  int idx = blockIdx.x * 4 + wv;  // b*256+t
  int b = idx >> 8, t = idx & 255;
  const unsigned short* hr = hsd + (size_t)idx * 1024 + l * 16;
  const float* wc = wcont + l * 16;
  const float* dr = d2 + (size_t)b * 1024 + l * 16;
  float sc = 0.f, ss = 0.f;
#pragma unroll
  for (int j = 0; j < 16; ++j) {
    float hf = h2f(hr[j]);
    sc += hf * wc[j];
    ss += hf * dr[j];
  }
#pragma unroll
  for (int off = 32; off; off >>= 1) {
    sc += __shfl_down(sc, off);
    ss += __shfl_down(ss, off);
  }
  if (l == 0) s0[idx] = sc + ss + absp[t] + biasp[0];
}

// ---------------------------------------------------------------------------
// Sequential novelty scan over t. One block per batch; summ in regs 4/thread.
// ---------------------------------------------------------------------------
__global__ __launch_bounds__(256, 1) void scan_kernel(
    const float* __restrict__ Anov, const unsigned short* __restrict__ hsd,
    const float* __restrict__ s0, float* __restrict__ out) {
  int b = blockIdx.x, tid = threadIdx.x, wv = tid >> 6, l = tid & 63;
  __shared__ float red[4];
  float summ[4] = {0.f, 0.f, 0.f, 0.f};
  const float* Ab = Anov + (size_t)b * 256 * 1024 + tid * 4;
  const unsigned short* hb = hsd + (size_t)b * 256 * 1024 + tid * 4;
  const float* sb = s0 + b * 256;
  float* ob = out + b * 256;
  f32x4 a = *(const f32x4*)Ab;
  us4 hv = *(const us4*)hb;
  for (int t = 0; t < 256; ++t) {
    f32x4 ac = a;
    us4 hc = hv;
    if (t < 255) {  // prefetch next iter, independent of the dependent chain
      a = *(const f32x4*)(Ab + (t + 1) * 1024);
      hv = *(const us4*)(hb + (t + 1) * 1024);
    }
    float p = ac[0] * tanhf_(summ[0]) + ac[1] * tanhf_(summ[1]) +
              ac[2] * tanhf_(summ[2]) + ac[3] * tanhf_(summ[3]);
#pragma unroll
    for (int off = 32; off; off >>= 1) p += __shfl_down(p, off);
    if (l == 0) red[wv] = p;
    __syncthreads();
    float nov = red[0] + red[1] + red[2] + red[3];
    float prob = sigf(sb[t] - nov);
    summ[0] += prob * h2f(hc[0]);
    summ[1] += prob * h2f(hc[1]);
    summ[2] += prob * h2f(hc[2]);
    summ[3] += prob * h2f(hc[3]);
    if (tid == 0) ob[t] = prob;
    __syncthreads();
  }
}

// ---------------------------------------------------------------------------
extern "C" void kernel_launch(void* const* d_in, const int* in_sizes, int n_in,
                              void* d_out, int out_size, void* d_ws,
                              size_t ws_size, hipStream_t stream) {
  const float* emb = (const float*)d_in[0];
  const float* wihf = (const float*)d_in[2];
  const float* whhf = (const float*)d_in[3];
  const float* bf_ = (const float*)d_in[4];
  const float* wihb = (const float*)d_in[5];
  const float* whhb = (const float*)d_in[6];
  const float* bb_ = (const float*)d_in[7];
  const float* Wfdoc = (const float*)d_in[8];
  const float* bfdoc = (const float*)d_in[9];
  const float* posemb = (const float*)d_in[10];
  const float* wcont = (const float*)d_in[11];
  const float* Wsal = (const float*)d_in[12];
  const float* Wnov = (const float*)d_in[13];
  const float* wabs = (const float*)d_in[14];
  const float* biasp = (const float*)d_in[15];

  char* ws = (char*)d_ws;
  unsigned short* PRE = (unsigned short*)(ws + 0);  // 134217728 B
  float* Anov = (float*)(ws + 0);                   // 67108864 B (reuses PRE)
  unsigned short* emb_t = (unsigned short*)(ws + 134217728);  // 25165824
  unsigned short* wcat = (unsigned short*)(ws + 159383552);   // 6291456
  unsigned short* whh = (unsigned short*)(ws + 165675008);    // 4194304
  unsigned short* WnT = (unsigned short*)(ws + 169869312);    // 2097152
  unsigned short* hsd = (unsigned short*)(ws + 171966464);    // 33554432
  unsigned short* hst = (unsigned short*)(ws + 205520896);    // 1048576
  float* hsum = (float*)(ws + 206569472);                     // 262144
  float* doc = (float*)(ws + 206831616);                      // 262144
  float* d2 = (float*)(ws + 207093760);                       // 262144
  float* s0 = (float*)(ws + 207355904);                       // 65536
  float* absp = (float*)(ws + 207421440);                     // 1024
  float* bcat = (float*)(ws + 207422464);                     // 16384
  int* cnt = (int*)(ws + 207438848);                          // 8192
  float* out = (float*)d_out;

  prep_kernel<<<dim3(2048), dim3(256), 0, stream>>>(
      emb, wihf, whhf, bf_, wihb, whhb, bb_, posemb, Wnov, wabs, emb_t, wcat,
      whh, WnT, bcat, absp, hst, cnt);
  gemm_bt<1, 1><<<dim3(32, 128), dim3(256), 0, stream>>>(
      wcat, emb_t, (void*)PRE, bcat, 4096, 16384, 768);
  lstm_kernel<<<dim3(256), dim3(256), 0, stream>>>(whh, PRE, hst, hsd, cnt);
  hsum_kernel<<<dim3(64), dim3(256), 0, stream>>>(hsd, hsum);
  rowdot_kernel<<<dim3(256), dim3(256), 0, stream>>>(Wfdoc, hsum, bfdoc, doc,
                                                     1.f / 256.f, 1);
  rowdot_kernel<<<dim3(256), dim3(256), 0, stream>>>(Wsal, doc, (const float*)nullptr,
                                                     d2, 1.f, 0);
  s0_kernel<<<dim3(4096), dim3(256), 0, stream>>>(hsd, wcont, d2, absp, biasp, s0);
  gemm_bt<0, 0><<<dim3(128, 8), dim3(256), 0, stream>>>(
      hsd, WnT, (void*)Anov, (const float*)nullptr, 16384, 1024, 1024);
  scan_kernel<<<dim3(64), dim3(256), 0, stream>>>(Anov, hsd, s0, out);
}